// Round 6
// baseline (397.617 us; speedup 1.0000x reference)
//
#include <hip/hip_runtime.h>
#include <hip/hip_fp16.h>

// W8X8Linear: per-row int8 quant (x and w), int8 GEMM via MFMA, dequant+bias.
// M=B*S=32768, N=1024, K=1024 (derived from in_sizes at launch).
//
// Exact-replication notes:
//  - jnp.round == round-half-even == rintf (v_rndne_f32)
//  - scale computed as 127.0f/max (fp32 div) then fp32 mul, like the reference
//  - int32 accumulation == reference's fp32 einsum (|acc| < 2^24, exact)
//  - dequant: * (1/16129) [was fp32 div; <=1 fp16-ulp diff, 3.8x margin],
//    fp16 RN cast, fp32 * (xmax*wmax) + bias
//
// R1: dbuf(drained) + XCD swizzle (FETCH 130->33 MB). ~92 us GEMM.
// R2: counted-vmcnt 3-buffer on 128^2: NULL — staged traffic (512 MB) is a
//     TA-transaction floor (~52us), schedule can't go below it.
// R3: no-LDS register GEMM: REGRESSED (16-line split loads; TA-bound 158us).
// R4: 256^2 3-buf lockstep: traffic halved (256MB) but 96KB LDS -> 1 blk/CU,
//     48 lockstep barriers with no overlap partner -> 117us.
// R5: 256^2 traffic + R1's simple schedule + 2 blocks/CU (64KB LDS, 2 bufs):
//     inter-block overlap hides the per-tile drain. Epilogue div->mul,
//     store order m,r,n for TCC line assembly.

typedef int i32x4 __attribute__((ext_vector_type(4)));

#define BM 256
#define BN 256
#define BKB 64  // K-bytes (= i8 elems) per K-tile

// ---------------- quantize: one block per row, K=1024, 256 threads ----------
__global__ __launch_bounds__(256) void quant_rows_kernel(
    const float* __restrict__ in, signed char* __restrict__ q,
    float* __restrict__ rowmax, int K) {
  const int row = blockIdx.x;
  const int t = threadIdx.x;
  const size_t base = (size_t)row * K;
  float4 v = reinterpret_cast<const float4*>(in + base)[t];
  float a = fmaxf(fmaxf(fabsf(v.x), fabsf(v.y)), fmaxf(fabsf(v.z), fabsf(v.w)));
#pragma unroll
  for (int off = 32; off > 0; off >>= 1) a = fmaxf(a, __shfl_xor(a, off, 64));
  __shared__ float smax[4];
  if ((t & 63) == 0) smax[t >> 6] = a;
  __syncthreads();
  float m = fmaxf(fmaxf(smax[0], smax[1]), fmaxf(smax[2], smax[3]));
  float s = 127.0f / m;  // fp32 divide, same as reference
  char4 qq;
  qq.x = (signed char)(int)rintf(v.x * s);
  qq.y = (signed char)(int)rintf(v.y * s);
  qq.z = (signed char)(int)rintf(v.z * s);
  qq.w = (signed char)(int)rintf(v.w * s);
  reinterpret_cast<char4*>(q + base)[t] = qq;
  if (t == 0) rowmax[row] = m;
}

// ---------------- int8 GEMM, 256x256 tile, 8 waves (2Mx4N) ------------------
__device__ __forceinline__ void gload_lds16(const void* g, void* l) {
  __builtin_amdgcn_global_load_lds(
      (const __attribute__((address_space(1))) unsigned char*)g,
      (__attribute__((address_space(3))) unsigned char*)l, 16, 0, 0);
}

__global__ __launch_bounds__(512, 4) void w8x8_gemm_kernel(
    const signed char* __restrict__ Aq, const signed char* __restrict__ Bq,
    const float* __restrict__ Amax, const float* __restrict__ Bmax,
    const float* __restrict__ bias, float* __restrict__ out,
    int M, int N, int K, int cpx) {
  // 2 K-tile buffers per operand: 2 * 256*64 = 32 KB each, 64 KB total
  // -> exactly 2 blocks/CU (the overlap partner R4 lacked).
  __shared__ __align__(16) signed char ldsA[2 * BM * BKB];
  __shared__ __align__(16) signed char ldsB[2 * BN * BKB];
  const int t = threadIdx.x;
  const int lane = t & 63;
  const int wave = t >> 6;
  const int wm = wave >> 2;  // 0..1  (M half)
  const int wn = wave & 3;   // 0..3  (N quarter)

  // XCD-chunked swizzle: 512 blocks, 64 per XCD -> per-XCD A slice 4 MB (L2).
  const int nbn = N / BN;  // 4
  const int bid = blockIdx.x;
  const int tile = (bid & 7) * cpx + (bid >> 3);
  const int bm = tile / nbn, bn = tile % nbn;

  const signed char* Abase = Aq + (size_t)bm * BM * K;
  const signed char* Bbase = Bq + (size_t)bn * BN * K;

  // Staging: K-tile = 256 rows x 64 B = 1024 16B-chunks; 512 thr x 2 chunks.
  // LDS dest linear (chunk c at byte c*16); global source pre-swizzled:
  // physical chunk p of row r holds logical chunk p ^ ((r>>1)&3).
  const int rS = t >> 2;                      // row of chunk t (t+512 -> +128)
  const int lcS = (t & 3) ^ ((rS >> 1) & 3);  // same XOR for both chunks
  const size_t gA0 = (size_t)rS * K + lcS * 16;
  const size_t gA1 = gA0 + (size_t)128 * K;
  const int dd0 = t * 16, dd1 = t * 16 + 8192;

  // Fragment reads (swizzled): lane(fr,fq) of frag-row r reads
  // r*64 + (fq ^ ((r>>1)&3))*16 ; (r>>1)&3 == (fr>>1)&3 for all our rows.
  const int fr = lane & 15, fq = lane >> 4;
  const int pc = fq ^ ((fr >> 1) & 3);
  const int aoff0 = (wm * 128 + fr) * BKB + pc * 16;
  const int boff0 = (wn * 64 + fr) * BKB + pc * 16;

  i32x4 acc[8][4];
#pragma unroll
  for (int m = 0; m < 8; ++m)
#pragma unroll
    for (int n = 0; n < 4; ++n) acc[m][n] = (i32x4){0, 0, 0, 0};

#define STAGE(bf, kt)                                                       \
  do {                                                                      \
    gload_lds16(Abase + gA0 + (size_t)(kt) * BKB, ldsA + (bf)*16384 + dd0); \
    gload_lds16(Abase + gA1 + (size_t)(kt) * BKB, ldsA + (bf)*16384 + dd1); \
    gload_lds16(Bbase + gA0 + (size_t)(kt) * BKB, ldsB + (bf)*16384 + dd0); \
    gload_lds16(Bbase + gA1 + (size_t)(kt) * BKB, ldsB + (bf)*16384 + dd1); \
  } while (0)

  const int NT = K / BKB;  // 16
  // Prologue: stage K-tile 0 into buf 0, drain, barrier.
  STAGE(0, 0);
  asm volatile("s_waitcnt vmcnt(0)" ::: "memory");
  __builtin_amdgcn_s_barrier();

  for (int kt = 0; kt < NT; ++kt) {
    const signed char* lA = ldsA + (kt & 1) * 16384;
    const signed char* lB = ldsB + (kt & 1) * 16384;
    const bool pf = (kt + 1 < NT);
    // 1) issue next tile's staging first (other buffer; safe: that buffer's
    //    readers all passed the previous barrier after their MFMAs consumed
    //    the ds_reads)
    if (pf) STAGE((kt + 1) & 1, kt + 1);

    // 2) compute current tile
    i32x4 a[8], b[4];
#pragma unroll
    for (int m = 0; m < 8; ++m)
      a[m] = *reinterpret_cast<const i32x4*>(lA + aoff0 + m * (16 * BKB));
#pragma unroll
    for (int n = 0; n < 4; ++n)
      b[n] = *reinterpret_cast<const i32x4*>(lB + boff0 + n * (16 * BKB));
    __builtin_amdgcn_s_setprio(1);
#pragma unroll
    for (int m = 0; m < 8; ++m)
#pragma unroll
      for (int n = 0; n < 4; ++n)
        acc[m][n] = __builtin_amdgcn_mfma_i32_16x16x64_i8(a[m], b[n],
                                                          acc[m][n], 0, 0, 0);
    __builtin_amdgcn_s_setprio(0);

    // 3) drain this iteration's staging + barrier; the stall overlaps the
    //    co-resident block's compute.
    if (pf) {
      asm volatile("s_waitcnt vmcnt(0)" ::: "memory");
      __builtin_amdgcn_s_barrier();
    }
  }
#undef STAGE

  // Epilogue: C/D layout col = lane&15, row = (lane>>4)*4 + reg.
  // Loop order m,r outer / n inner so a row's 4x64B segments are written
  // back-to-back (TCC 128B line assembly).
  const int row0 = bm * BM + wm * 128;
  const int col0 = bn * BN + wn * 64;
  const float C = 1.0f / 16129.0f;
  float wmx[4], bs[4];
#pragma unroll
  for (int n = 0; n < 4; ++n) {
    int col = col0 + n * 16 + fr;
    wmx[n] = Bmax[col];
    bs[n] = bias[col];
  }
#pragma unroll
  for (int m = 0; m < 8; ++m) {
#pragma unroll
    for (int r = 0; r < 4; ++r) {
      int row = row0 + m * 16 + fq * 4 + r;
      float xm = Amax[row];
      float* orow = out + (size_t)row * N;
#pragma unroll
      for (int n = 0; n < 4; ++n) {
        float v = (float)acc[m][n][r] * C;            // recip-mul (see notes)
        float h = __half2float(__float2half_rn(v));   // fp16 rounding step
        orow[col0 + n * 16 + fr] = h * (xm * wmx[n]) + bs[n];
      }
    }
  }
}

extern "C" void kernel_launch(void* const* d_in, const int* in_sizes, int n_in,
                              void* d_out, int out_size, void* d_ws, size_t ws_size,
                              hipStream_t stream) {
  const float* x = (const float*)d_in[0];     // [B,S,K] fp32
  const float* w = (const float*)d_in[1];     // [N,K] fp32
  const float* bias = (const float*)d_in[2];  // [N] fp32
  float* out = (float*)d_out;                 // [B,S,N] fp32

  const int N = in_sizes[2];
  const int K = in_sizes[1] / N;   // 1024
  const int M = in_sizes[0] / K;   // 32768

  // workspace layout: x_q | w_q | x_max | w_max  (~34.7 MB total)
  signed char* xq = (signed char*)d_ws;
  signed char* wq = xq + (size_t)M * K;
  float* xmax = (float*)(wq + (size_t)N * K);
  float* wmax = xmax + M;

  quant_rows_kernel<<<M, 256, 0, stream>>>(x, xq, xmax, K);
  quant_rows_kernel<<<N, 256, 0, stream>>>(w, wq, wmax, K);

  const int nwg = (M / BM) * (N / BN);  // 512, divisible by 8
  const int cpx = nwg / 8;
  w8x8_gemm_kernel<<<nwg, 512, 0, stream>>>(xq, wq, xmax, wmax, bias, out,
                                            M, N, K, cpx);
}

// Round 7
// 95.120 us; speedup vs baseline: 4.1802x; 4.1802x over previous
//
#include <hip/hip_runtime.h>
#include <hip/hip_fp16.h>

// W8X8Linear: per-row int8 quant (x and w), int8 GEMM via MFMA, dequant+bias.
// M=B*S=32768, S=8192, N=1024, K=1024 (derived from in_sizes at launch).
//
// Exact-replication notes:
//  - jnp.round == round-half-even == rintf (v_rndne_f32)
//  - scale computed as 127.0f/max (fp32 div) then fp32 mul, like the reference
//  - int32 accumulation == reference's fp32 einsum (|acc| < 2^24, exact)
//  - dequant: * (1/16129), fp16 RN cast, fp32 * (xmax*wmax) + bias
//
// R1: dbuf(drained) + XCD swizzle (FETCH 130->33 MB). ~92 us GEMM.
// R2: counted-vmcnt 3-buffer: NULL. R3: no-LDS reg GEMM: 158 us (16-segment
//     flat loads -> VMEM coalescer probe-bound). R4: 256^2 fine-phase: worse.
// R5: launch_bounds(512,4) forced VGPR<=128 -> acc spilled -> 360 us. Also
//     identified the REAL shared floor: every gload_lds statement stages
//     16 discontiguous 64-B segments (rows 1024 B apart) -> ~4cy/segment
//     probe -> ~54 us of serialized VMEM issue across all structures.
// R6: K-BLOCKED quant layout q[kb][row][128] makes each staged tile one
//     contiguous 16 KB region: 1-KB-contiguous wave statements (1 segment).
//     BK=128 (8 iters, 32 MFMA/wave/iter), 2 bufs (64 KB -> 2 blocks/CU),
//     XOR-swizzle (row&7)<<4 via pre-swizzled source + swizzled ds_read.

typedef int i32x4 __attribute__((ext_vector_type(4)));

#define BM 128
#define BN 128
#define BKB 128  // K-bytes per tile = quant layout block size

// -------- quantize: one block per row; OUTPUT IS K-BLOCKED q[kb][row][128] --
__global__ __launch_bounds__(256) void quant_rows_kernel(
    const float* __restrict__ in, signed char* __restrict__ q,
    float* __restrict__ rowmax, int K, int R) {
  const int row = blockIdx.x;
  const int t = threadIdx.x;
  const size_t base = (size_t)row * K;
  float4 v = reinterpret_cast<const float4*>(in + base)[t];
  float a = fmaxf(fmaxf(fabsf(v.x), fabsf(v.y)), fmaxf(fabsf(v.z), fabsf(v.w)));
#pragma unroll
  for (int off = 32; off > 0; off >>= 1) a = fmaxf(a, __shfl_xor(a, off, 64));
  __shared__ float smax[4];
  if ((t & 63) == 0) smax[t >> 6] = a;
  __syncthreads();
  float m = fmaxf(fmaxf(smax[0], smax[1]), fmaxf(smax[2], smax[3]));
  float s = 127.0f / m;  // fp32 divide, same as reference
  char4 qq;
  qq.x = (signed char)(int)rintf(v.x * s);
  qq.y = (signed char)(int)rintf(v.y * s);
  qq.z = (signed char)(int)rintf(v.z * s);
  qq.w = (signed char)(int)rintf(v.w * s);
  // elems k = 4t..4t+3 -> kb = t>>5, within-block byte (t&31)*4
  const int kb = t >> 5;
  signed char* dst =
      q + (size_t)kb * R * BKB + (size_t)row * BKB + (t & 31) * 4;
  *reinterpret_cast<char4*>(dst) = qq;
  if (t == 0) rowmax[row] = m;
}

// ---------------- int8 GEMM, 128x128 tile, 4 waves (2x2), BK=128 ------------
__device__ __forceinline__ void gload_lds16(const void* g, void* l) {
  __builtin_amdgcn_global_load_lds(
      (const __attribute__((address_space(1))) unsigned char*)g,
      (__attribute__((address_space(3))) unsigned char*)l, 16, 0, 0);
}

__global__ __launch_bounds__(256) void w8x8_gemm_kernel(
    const signed char* __restrict__ Aq, const signed char* __restrict__ Bq,
    const float* __restrict__ Amax, const float* __restrict__ Bmax,
    const float* __restrict__ bias, float* __restrict__ out,
    int M, int N, int K, int cpx) {
  // 2 buffers x (A 16 KB + B 16 KB) = 64 KB -> 2 blocks/CU.
  __shared__ __align__(16) signed char ldsA[2][BM * BKB];
  __shared__ __align__(16) signed char ldsB[2][BN * BKB];
  const int t = threadIdx.x;
  const int lane = t & 63;
  const int wave = t >> 6;
  const int wrow = wave >> 1, wcol = wave & 1;

  // XCD-chunked swizzle: contiguous bm-run per XCD (A slice 4 MB = one L2).
  const int nbn = N / BN;
  const int bid = blockIdx.x;
  const int tile = (bid & 7) * cpx + (bid >> 3);
  const int bm = tile / nbn, bn = tile % nbn;

  // K-blocked layout: operand tile for k-block kt is CONTIGUOUS 16 KB at
  // q + kt*R*128 + tilerow0*128.
  const size_t kbStrideA = (size_t)M * BKB;
  const size_t kbStrideB = (size_t)N * BKB;
  const signed char* Abase = Aq + (size_t)bm * BM * BKB;
  const signed char* Bbase = Bq + (size_t)bn * BN * BKB;

  // Staging: statement s covers LDS bytes [s*4096 + t*16, +16). Source is
  // pre-swizzled so that phys[D] = logical[D ^ ((row(D)&7)<<4)], row = D>>7.
  // (row&7) == (t>>3)&7 for all s (s*4096 is a multiple of 8 rows).
  const int soff = (t * 16) ^ (((t >> 3) & 7) << 4);

  // Fragment reads (swizzled): logical byte for row r, k-step ks, lane fq:
  // r*128 + ((ks*4+fq) ^ (r&7))*16
  const int fr = lane & 15, fq = lane >> 4;
  int aoff[4][2], boff[4][2];
#pragma unroll
  for (int m = 0; m < 4; ++m) {
    int ra = wrow * 64 + m * 16 + fr;
    int rb = wcol * 64 + m * 16 + fr;
#pragma unroll
    for (int ks = 0; ks < 2; ++ks) {
      aoff[m][ks] = ra * BKB + (((ks << 2) | fq) ^ (ra & 7)) * 16;
      boff[m][ks] = rb * BKB + (((ks << 2) | fq) ^ (rb & 7)) * 16;
    }
  }

  i32x4 acc[4][4];
#pragma unroll
  for (int m = 0; m < 4; ++m)
#pragma unroll
    for (int n = 0; n < 4; ++n) acc[m][n] = (i32x4){0, 0, 0, 0};

#define STAGE(bf, kt)                                                        \
  do {                                                                       \
    const signed char* ga = Abase + (size_t)(kt)*kbStrideA;                  \
    const signed char* gb = Bbase + (size_t)(kt)*kbStrideB;                  \
    gload_lds16(ga + soff, &ldsA[bf][t * 16]);                               \
    gload_lds16(ga + 4096 + soff, &ldsA[bf][4096 + t * 16]);                 \
    gload_lds16(ga + 8192 + soff, &ldsA[bf][8192 + t * 16]);                 \
    gload_lds16(ga + 12288 + soff, &ldsA[bf][12288 + t * 16]);               \
    gload_lds16(gb + soff, &ldsB[bf][t * 16]);                               \
    gload_lds16(gb + 4096 + soff, &ldsB[bf][4096 + t * 16]);                 \
    gload_lds16(gb + 8192 + soff, &ldsB[bf][8192 + t * 16]);                 \
    gload_lds16(gb + 12288 + soff, &ldsB[bf][12288 + t * 16]);               \
  } while (0)

  const int NT = K / BKB;  // 8
  STAGE(0, 0);
  asm volatile("s_waitcnt vmcnt(0)" ::: "memory");
  __builtin_amdgcn_s_barrier();

  for (int kt = 0; kt < NT; ++kt) {
    const signed char* lA = ldsA[kt & 1];
    const signed char* lB = ldsB[kt & 1];
    const bool pf = (kt + 1 < NT);
    if (pf) STAGE((kt + 1) & 1, kt + 1);

#pragma unroll
    for (int ks = 0; ks < 2; ++ks) {
      i32x4 a[4], b[4];
#pragma unroll
      for (int m = 0; m < 4; ++m) {
        a[m] = *reinterpret_cast<const i32x4*>(lA + aoff[m][ks]);
        b[m] = *reinterpret_cast<const i32x4*>(lB + boff[m][ks]);
      }
      __builtin_amdgcn_s_setprio(1);
#pragma unroll
      for (int m = 0; m < 4; ++m)
#pragma unroll
        for (int n = 0; n < 4; ++n)
          acc[m][n] = __builtin_amdgcn_mfma_i32_16x16x64_i8(a[m], b[n],
                                                            acc[m][n], 0, 0, 0);
      __builtin_amdgcn_s_setprio(0);
    }

    if (pf) {
      asm volatile("s_waitcnt vmcnt(0)" ::: "memory");
      __builtin_amdgcn_s_barrier();
    }
  }
#undef STAGE

  // Epilogue: C/D layout col = lane&15, row = (lane>>4)*4 + reg.
  const int row0 = bm * BM + wrow * 64;
  const int col0 = bn * BN + wcol * 64;
  const float C = 1.0f / 16129.0f;
  float wmx[4], bs[4];
#pragma unroll
  for (int n = 0; n < 4; ++n) {
    int col = col0 + n * 16 + fr;
    wmx[n] = Bmax[col];
    bs[n] = bias[col];
  }
#pragma unroll
  for (int m = 0; m < 4; ++m) {
#pragma unroll
    for (int r = 0; r < 4; ++r) {
      int row = row0 + m * 16 + fq * 4 + r;
      float xm = Amax[row];
      float* orow = out + (size_t)row * N;
#pragma unroll
      for (int n = 0; n < 4; ++n) {
        float v = (float)acc[m][n][r] * C;
        float h = __half2float(__float2half_rn(v));  // fp16 rounding step
        orow[col0 + n * 16 + fr] = h * (xm * wmx[n]) + bs[n];
      }
    }
  }
}

extern "C" void kernel_launch(void* const* d_in, const int* in_sizes, int n_in,
                              void* d_out, int out_size, void* d_ws, size_t ws_size,
                              hipStream_t stream) {
  const float* x = (const float*)d_in[0];     // [B,S,K] fp32
  const float* w = (const float*)d_in[1];     // [N,K] fp32
  const float* bias = (const float*)d_in[2];  // [N] fp32
  float* out = (float*)d_out;                 // [B,S,N] fp32

  const int N = in_sizes[2];
  const int K = in_sizes[1] / N;   // 1024
  const int M = in_sizes[0] / K;   // 32768

  // workspace layout: x_q | w_q | x_max | w_max  (~34.7 MB total)
  signed char* xq = (signed char*)d_ws;
  signed char* wq = xq + (size_t)M * K;
  float* xmax = (float*)(wq + (size_t)N * K);
  float* wmax = xmax + M;

  quant_rows_kernel<<<M, 256, 0, stream>>>(x, xq, xmax, K, M);
  quant_rows_kernel<<<N, 256, 0, stream>>>(w, wq, wmax, K, N);

  const int nwg = (M / BM) * (N / BN);  // 2048, divisible by 8
  const int cpx = nwg / 8;
  w8x8_gemm_kernel<<<nwg, 256, 0, stream>>>(xq, wq, xmax, wmax, bias, out,
                                            M, N, K, cpx);
}

// Round 8
// 94.256 us; speedup vs baseline: 4.2185x; 1.0092x over previous
//
#include <hip/hip_runtime.h>
#include <hip/hip_fp16.h>

// W8X8Linear: per-row int8 quant (x and w), int8 GEMM via MFMA, dequant+bias.
// M=B*S=32768, S=8192, N=1024, K=1024 (derived from in_sizes at launch).
//
// Exact-replication notes:
//  - jnp.round == round-half-even == rintf (v_rndne_f32)
//  - scale computed as 127.0f/max (fp32 div) then fp32 mul, like the reference
//  - int32 accumulation == reference's fp32 einsum (|acc| < 2^24, exact)
//  - dequant: * (1/16129), fp16 RN cast, fp32 * (xmax*wmax) + bias
//
// R1: dbuf(drained)+XCD swizzle: 92us GEMM. R2: counted-vmcnt 3-buf: NULL
//     (segment-probe floor masked it). R3: no-LDS reg GEMM: 158us (16-seg
//     loads). R4: 256^2 fine-phase 1blk/CU: 117us. R5: launch_bounds min-wave
//     forced spill: 360us.
// R6: K-BLOCKED quant layout q[kb][row][128] -> every staging statement is
//     1-KB-contiguous per wave. 95us total (~60us GEMM). Budget shows pipes
//     ~fully serialized: drain-at-bottom vmcnt(0) gives the prefetch only the
//     current iteration's compute as cover, then locksteps.
// R7: rotate the wait to the TOP and COUNT it: stage(kt+1) -> vmcnt(8)
//     (waits tile kt staged LAST iter = full iteration of cover; kt+1's 8
//     loads stay in flight ACROSS the barrier) -> barrier -> compute ->
//     barrier. Never drain to 0 in the loop (T4, m218).

typedef int i32x4 __attribute__((ext_vector_type(4)));

#define BM 128
#define BN 128
#define BKB 128  // K-bytes per tile = quant layout block size

// -------- quantize: one block per row; OUTPUT IS K-BLOCKED q[kb][row][128] --
__global__ __launch_bounds__(256) void quant_rows_kernel(
    const float* __restrict__ in, signed char* __restrict__ q,
    float* __restrict__ rowmax, int K, int R) {
  const int row = blockIdx.x;
  const int t = threadIdx.x;
  const size_t base = (size_t)row * K;
  float4 v = reinterpret_cast<const float4*>(in + base)[t];
  float a = fmaxf(fmaxf(fabsf(v.x), fabsf(v.y)), fmaxf(fabsf(v.z), fabsf(v.w)));
#pragma unroll
  for (int off = 32; off > 0; off >>= 1) a = fmaxf(a, __shfl_xor(a, off, 64));
  __shared__ float smax[4];
  if ((t & 63) == 0) smax[t >> 6] = a;
  __syncthreads();
  float m = fmaxf(fmaxf(smax[0], smax[1]), fmaxf(smax[2], smax[3]));
  float s = 127.0f / m;  // fp32 divide, same as reference
  char4 qq;
  qq.x = (signed char)(int)rintf(v.x * s);
  qq.y = (signed char)(int)rintf(v.y * s);
  qq.z = (signed char)(int)rintf(v.z * s);
  qq.w = (signed char)(int)rintf(v.w * s);
  // elems k = 4t..4t+3 -> kb = t>>5, within-block byte (t&31)*4
  const int kb = t >> 5;
  signed char* dst =
      q + (size_t)kb * R * BKB + (size_t)row * BKB + (t & 31) * 4;
  *reinterpret_cast<char4*>(dst) = qq;
  if (t == 0) rowmax[row] = m;
}

// ---------------- int8 GEMM, 128x128 tile, 4 waves (2x2), BK=128 ------------
__device__ __forceinline__ void gload_lds16(const void* g, void* l) {
  __builtin_amdgcn_global_load_lds(
      (const __attribute__((address_space(1))) unsigned char*)g,
      (__attribute__((address_space(3))) unsigned char*)l, 16, 0, 0);
}

__global__ __launch_bounds__(256) void w8x8_gemm_kernel(
    const signed char* __restrict__ Aq, const signed char* __restrict__ Bq,
    const float* __restrict__ Amax, const float* __restrict__ Bmax,
    const float* __restrict__ bias, float* __restrict__ out,
    int M, int N, int K, int cpx) {
  // 2 buffers x (A 16 KB + B 16 KB) = 64 KB -> 2 blocks/CU.
  __shared__ __align__(16) signed char ldsA[2][BM * BKB];
  __shared__ __align__(16) signed char ldsB[2][BN * BKB];
  const int t = threadIdx.x;
  const int lane = t & 63;
  const int wave = t >> 6;
  const int wrow = wave >> 1, wcol = wave & 1;

  // XCD-chunked swizzle: contiguous bm-run per XCD (A slice 4 MB = one L2).
  const int nbn = N / BN;
  const int bid = blockIdx.x;
  const int tile = (bid & 7) * cpx + (bid >> 3);
  const int bm = tile / nbn, bn = tile % nbn;

  // K-blocked layout: operand tile for k-block kt is CONTIGUOUS 16 KB at
  // q + kt*R*128 + tilerow0*128.
  const size_t kbStrideA = (size_t)M * BKB;
  const size_t kbStrideB = (size_t)N * BKB;
  const signed char* Abase = Aq + (size_t)bm * BM * BKB;
  const signed char* Bbase = Bq + (size_t)bn * BN * BKB;

  // Staging: statement s covers LDS bytes [s*4096 + t*16, +16). Source is
  // pre-swizzled so that phys[D] = logical[D ^ ((row(D)&7)<<4)], row = D>>7.
  // (row&7) == (t>>3)&7 for all s (s*4096 is a multiple of 8 rows).
  const int soff = (t * 16) ^ (((t >> 3) & 7) << 4);

  // Fragment reads (swizzled): logical byte for row r, k-step ks, lane fq:
  // r*128 + ((ks*4+fq) ^ (r&7))*16  -> 2-way bank aliasing (free).
  const int fr = lane & 15, fq = lane >> 4;
  int aoff[4][2], boff[4][2];
#pragma unroll
  for (int m = 0; m < 4; ++m) {
    int ra = wrow * 64 + m * 16 + fr;
    int rb = wcol * 64 + m * 16 + fr;
#pragma unroll
    for (int ks = 0; ks < 2; ++ks) {
      aoff[m][ks] = ra * BKB + (((ks << 2) | fq) ^ (ra & 7)) * 16;
      boff[m][ks] = rb * BKB + (((ks << 2) | fq) ^ (rb & 7)) * 16;
    }
  }

  i32x4 acc[4][4];
#pragma unroll
  for (int m = 0; m < 4; ++m)
#pragma unroll
    for (int n = 0; n < 4; ++n) acc[m][n] = (i32x4){0, 0, 0, 0};

#define STAGE(bf, kt)                                                        \
  do {                                                                       \
    const signed char* ga = Abase + (size_t)(kt)*kbStrideA;                  \
    const signed char* gb = Bbase + (size_t)(kt)*kbStrideB;                  \
    gload_lds16(ga + soff, &ldsA[bf][t * 16]);                               \
    gload_lds16(ga + 4096 + soff, &ldsA[bf][4096 + t * 16]);                 \
    gload_lds16(ga + 8192 + soff, &ldsA[bf][8192 + t * 16]);                 \
    gload_lds16(ga + 12288 + soff, &ldsA[bf][12288 + t * 16]);               \
    gload_lds16(gb + soff, &ldsB[bf][t * 16]);                               \
    gload_lds16(gb + 4096 + soff, &ldsB[bf][4096 + t * 16]);                 \
    gload_lds16(gb + 8192 + soff, &ldsB[bf][8192 + t * 16]);                 \
    gload_lds16(gb + 12288 + soff, &ldsB[bf][12288 + t * 16]);               \
  } while (0)

  const int NT = K / BKB;  // 8
  // Prologue: stage tile 0 only; the loop's first vmcnt covers it.
  STAGE(0, 0);

  for (int kt = 0; kt < NT; ++kt) {
    const bool pf = (kt + 1 < NT);
    // 1) issue next tile's staging (other buffer; its readers passed the
    //    end-of-(kt-1) barrier)
    if (pf) STAGE((kt + 1) & 1, kt + 1);
    // 2) counted wait: tile kt's 8 loads (issued LAST iteration -> a full
    //    iteration of compute as latency cover) retired; tile kt+1's 8
    //    stay in flight ACROSS the barrier. In-order retirement (m135)
    //    makes vmcnt(8) <=> "tile kt fully landed".
    if (pf)
      asm volatile("s_waitcnt vmcnt(8)" ::: "memory");
    else
      asm volatile("s_waitcnt vmcnt(0)" ::: "memory");
    __builtin_amdgcn_s_barrier();  // all waves' tile-kt loads landed

    // 3) compute tile kt
    const signed char* lA = ldsA[kt & 1];
    const signed char* lB = ldsB[kt & 1];
#pragma unroll
    for (int ks = 0; ks < 2; ++ks) {
      i32x4 a[4], b[4];
#pragma unroll
      for (int m = 0; m < 4; ++m) {
        a[m] = *reinterpret_cast<const i32x4*>(lA + aoff[m][ks]);
        b[m] = *reinterpret_cast<const i32x4*>(lB + boff[m][ks]);
      }
      __builtin_amdgcn_s_setprio(1);
#pragma unroll
      for (int m = 0; m < 4; ++m)
#pragma unroll
        for (int n = 0; n < 4; ++n)
          acc[m][n] = __builtin_amdgcn_mfma_i32_16x16x64_i8(a[m], b[n],
                                                            acc[m][n], 0, 0, 0);
      __builtin_amdgcn_s_setprio(0);
    }

    // 4) barrier so next iteration's stage can't overwrite a buffer a
    //    lagging wave is still reading. No vmcnt here (the whole point).
    if (pf) __builtin_amdgcn_s_barrier();
  }
#undef STAGE

  // Epilogue: C/D layout col = lane&15, row = (lane>>4)*4 + reg.
  const int row0 = bm * BM + wrow * 64;
  const int col0 = bn * BN + wcol * 64;
  const float C = 1.0f / 16129.0f;
  float wmx[4], bs[4];
#pragma unroll
  for (int n = 0; n < 4; ++n) {
    int col = col0 + n * 16 + fr;
    wmx[n] = Bmax[col];
    bs[n] = bias[col];
  }
#pragma unroll
  for (int m = 0; m < 4; ++m) {
#pragma unroll
    for (int r = 0; r < 4; ++r) {
      int row = row0 + m * 16 + fq * 4 + r;
      float xm = Amax[row];
      float* orow = out + (size_t)row * N;
#pragma unroll
      for (int n = 0; n < 4; ++n) {
        float v = (float)acc[m][n][r] * C;
        float h = __half2float(__float2half_rn(v));  // fp16 rounding step
        orow[col0 + n * 16 + fr] = h * (xm * wmx[n]) + bs[n];
      }
    }
  }
}

extern "C" void kernel_launch(void* const* d_in, const int* in_sizes, int n_in,
                              void* d_out, int out_size, void* d_ws, size_t ws_size,
                              hipStream_t stream) {
  const float* x = (const float*)d_in[0];     // [B,S,K] fp32
  const float* w = (const float*)d_in[1];     // [N,K] fp32
  const float* bias = (const float*)d_in[2];  // [N] fp32
  float* out = (float*)d_out;                 // [B,S,N] fp32

  const int N = in_sizes[2];
  const int K = in_sizes[1] / N;   // 1024
  const int M = in_sizes[0] / K;   // 32768

  // workspace layout: x_q | w_q | x_max | w_max  (~34.7 MB total)
  signed char* xq = (signed char*)d_ws;
  signed char* wq = xq + (size_t)M * K;
  float* xmax = (float*)(wq + (size_t)N * K);
  float* wmax = xmax + M;

  quant_rows_kernel<<<M, 256, 0, stream>>>(x, xq, xmax, K, M);
  quant_rows_kernel<<<N, 256, 0, stream>>>(w, wq, wmax, K, N);

  const int nwg = (M / BM) * (N / BN);  // 2048, divisible by 8
  const int cpx = nwg / 8;
  w8x8_gemm_kernel<<<nwg, 256, 0, stream>>>(xq, wq, xmax, wmax, bias, out,
                                            M, N, K, cpx);
}